// Round 3
// baseline (1305.625 us; speedup 1.0000x reference)
//
#include <hip/hip_runtime.h>
#include <hip/hip_fp16.h>
#include <cstdint>

#define T_DIM 1024
#define B_DIM 256
#define D_DIM 128
#define H_DIM 128
#define G_DIM 512

typedef _Float16 h2_t __attribute__((ext_vector_type(2)));

__device__ __forceinline__ float fastrcp(float x) {
#if __has_builtin(__builtin_amdgcn_rcpf)
    return __builtin_amdgcn_rcpf(x);
#else
    return 1.0f / x;
#endif
}

__device__ __forceinline__ float sigm(float x) {
    return fastrcp(1.0f + __expf(-x));
}

// tanh(x) = 1 - 2/(exp(2x)+1); saturates correctly via exp overflow/underflow.
__device__ __forceinline__ float tanh_fast(float x) {
    return 1.0f - 2.0f * fastrcp(1.0f + __expf(2.0f * x));
}

__device__ __forceinline__ float dot2(unsigned int a, unsigned int b, float acc) {
#if __has_builtin(__builtin_amdgcn_fdot2)
    return __builtin_amdgcn_fdot2(__builtin_bit_cast(h2_t, a),
                                  __builtin_bit_cast(h2_t, b), acc, false);
#else
    h2_t av = __builtin_bit_cast(h2_t, a);
    h2_t bv = __builtin_bit_cast(h2_t, b);
    return acc + (float)av.x * (float)bv.x + (float)av.y * (float)bv.y;
#endif
}

__device__ __forceinline__ unsigned int packh2(float a, float b) {
    h2_t v;
    v.x = (_Float16)a;
    v.y = (_Float16)b;
    return __builtin_bit_cast(unsigned int, v);
}

// One WG per batch element (256 WGs = 1 per CU). 512 threads: thread j owns
// gate column j; holds Wi[:,j] and Wh[:,j] as 64+64 packed-f16 VGPRs.
// Per step: gates via v_dot2_f32_f16 against x/h broadcast from LDS,
// activations on all 512 threads, carry update on threads 0..127.
// x_t / done prefetched 2 steps ahead (static parity regs, 2-step unroll).
__global__ __launch_bounds__(512, 2) void lstm_scan_kernel(
    const float* __restrict__ obs, const int* __restrict__ done,
    const float* __restrict__ c0, const float* __restrict__ h0,
    const float* __restrict__ Wi, const float* __restrict__ Wh,
    const float* __restrict__ bvec, float* __restrict__ out)
{
    const int b   = blockIdx.x;
    const int tid = threadIdx.x;

    __shared__ __align__(16) __half xh_h[2][D_DIM];  // x_t as f16, per parity
    __shared__ __align__(16) __half hh_h[2][H_DIM];  // h_t as f16, per parity
    __shared__ float gact[G_DIM];                    // activated gates
    __shared__ int   dflag[2];                       // done flag, per parity

    // ---- weight prologue: coalesced f32 loads -> packed f16 register file ----
    unsigned int wi[64], wh[64];
#pragma unroll
    for (int k2 = 0; k2 < 64; ++k2) {
        float a0 = Wi[(size_t)(2 * k2 + 0) * G_DIM + tid];
        float a1 = Wi[(size_t)(2 * k2 + 1) * G_DIM + tid];
        wi[k2] = packh2(a0, a1);
        float b0 = Wh[(size_t)(2 * k2 + 0) * G_DIM + tid];
        float b1 = Wh[(size_t)(2 * k2 + 1) * G_DIM + tid];
        wh[k2] = packh2(b0, b1);
    }
    const float bias = bvec[tid];

    float creg = 0.f, hreg = 0.f;
    float xr0 = 0.f, xr1 = 0.f;   // x prefetch slots (parity 0 / 1)
    int   dr0 = 0,  dr1 = 0;      // done prefetch slots

    if (tid < H_DIM) {
        creg = c0[b * H_DIM + tid];
        hh_h[0][tid] = __float2half(h0[b * H_DIM + tid]);
        xh_h[0][tid] = __float2half(obs[(size_t)(0 * B_DIM + b) * D_DIM + tid]);
        xr1 = obs[(size_t)(1 * B_DIM + b) * D_DIM + tid];
    }
    if (tid == 128) {
        dflag[0] = done[0 * B_DIM + b];
        dr1 = done[1 * B_DIM + b];
    }
    __syncthreads();

#define STEP(T_, P_, PN_, XRP_, XRPN_, DRP_, DRPN_)                            \
    {                                                                          \
        const int t = (T_);                                                    \
        int tf = t + 2; if (tf > T_DIM - 1) tf = T_DIM - 1;                    \
        float xnew = 0.f; int dnew = 0;                                        \
        if (tid < D_DIM) xnew = obs[((size_t)tf * B_DIM + b) * D_DIM + tid];   \
        if (tid == 128)  dnew = done[tf * B_DIM + b];                          \
        const int dm = dflag[P_];                                              \
        float xs0 = 0.f, xs1 = 0.f, xs2 = 0.f, xs3 = 0.f;                      \
        {                                                                      \
            const uint4* xp = (const uint4*)&xh_h[P_][0];                      \
            _Pragma("unroll")                                                  \
            for (int cc = 0; cc < 16; ++cc) {                                  \
                uint4 v = xp[cc];                                              \
                xs0 = dot2(v.x, wi[cc * 4 + 0], xs0);                          \
                xs1 = dot2(v.y, wi[cc * 4 + 1], xs1);                          \
                xs2 = dot2(v.z, wi[cc * 4 + 2], xs2);                          \
                xs3 = dot2(v.w, wi[cc * 4 + 3], xs3);                          \
            }                                                                  \
        }                                                                      \
        float gate = bias + ((xs0 + xs1) + (xs2 + xs3));                       \
        if (!dm) { /* block-uniform branch: skip h-dot on reset steps */       \
            float hs0 = 0.f, hs1 = 0.f, hs2 = 0.f, hs3 = 0.f;                  \
            const uint4* hp = (const uint4*)&hh_h[P_][0];                      \
            _Pragma("unroll")                                                  \
            for (int cc = 0; cc < 16; ++cc) {                                  \
                uint4 v = hp[cc];                                              \
                hs0 = dot2(v.x, wh[cc * 4 + 0], hs0);                          \
                hs1 = dot2(v.y, wh[cc * 4 + 1], hs1);                          \
                hs2 = dot2(v.z, wh[cc * 4 + 2], hs2);                          \
                hs3 = dot2(v.w, wh[cc * 4 + 3], hs3);                          \
            }                                                                  \
            gate += (hs0 + hs1) + (hs2 + hs3);                                 \
        }                                                                      \
        /* gate order i,f,g,o: g (cols 256..383) gets tanh -> wave-uniform */  \
        float act = (tid >= 256 && tid < 384) ? tanh_fast(gate) : sigm(gate);  \
        gact[tid] = act;                                                       \
        __syncthreads();                                                       \
        if (tid < H_DIM) {                                                     \
            float ai = gact[tid];                                              \
            float af = gact[tid + 128];                                        \
            float ag = gact[tid + 256];                                        \
            float ao = gact[tid + 384];                                        \
            float cp = dm ? 0.f : creg;                                        \
            creg = af * cp + ai * ag;                                          \
            float hn = ao * tanh_fast(creg);                                   \
            out[((size_t)t * B_DIM + b) * H_DIM + tid] = hn;                   \
            hreg = hn;                                                         \
            hh_h[PN_][tid] = __float2half(hn);                                 \
            xh_h[PN_][tid] = __float2half(XRPN_);                              \
            XRP_ = xnew;                                                       \
        }                                                                      \
        if (tid == 128) { dflag[PN_] = DRPN_; DRP_ = dnew; }                   \
        __syncthreads();                                                       \
    }

#pragma unroll 1
    for (int t2 = 0; t2 < T_DIM; t2 += 2) {
        STEP(t2 + 0, 0, 1, xr0, xr1, dr0, dr1)
        STEP(t2 + 1, 1, 0, xr1, xr0, dr1, dr0)
    }
#undef STEP

    // final carry outputs: c_f then h_f, appended after y
    if (tid < H_DIM) {
        const size_t ybase = (size_t)T_DIM * B_DIM * H_DIM;
        out[ybase + (size_t)b * H_DIM + tid] = creg;
        out[ybase + (size_t)B_DIM * H_DIM + (size_t)b * H_DIM + tid] = hreg;
    }
}

extern "C" void kernel_launch(void* const* d_in, const int* in_sizes, int n_in,
                              void* d_out, int out_size, void* d_ws, size_t ws_size,
                              hipStream_t stream) {
    const float* obs  = (const float*)d_in[0];
    const int*   done = (const int*)d_in[1];
    const float* c0   = (const float*)d_in[2];
    const float* h0   = (const float*)d_in[3];
    const float* Wi   = (const float*)d_in[4];
    const float* Wh   = (const float*)d_in[5];
    const float* bv   = (const float*)d_in[6];
    float* out = (float*)d_out;

    lstm_scan_kernel<<<dim3(B_DIM), dim3(512), 0, stream>>>(
        obs, done, c0, h0, Wi, Wh, bv, out);
}

// Round 5
// 933.351 us; speedup vs baseline: 1.3989x; 1.3989x over previous
//
#include <hip/hip_runtime.h>
#include <hip/hip_fp16.h>
#include <cstdint>

#define T_DIM 1024
#define B_DIM 256
#define D_DIM 128
#define H_DIM 128
#define G_DIM 512
#define CH    16   // timesteps per X-chunk (MFMA M-tile over time)

typedef _Float16 h2_t  __attribute__((ext_vector_type(2)));
typedef _Float16 f16x8 __attribute__((ext_vector_type(8)));
typedef float    f32x4 __attribute__((ext_vector_type(4)));

__device__ __forceinline__ float fastrcp(float x) {
#if __has_builtin(__builtin_amdgcn_rcpf)
    return __builtin_amdgcn_rcpf(x);
#else
    return 1.0f / x;
#endif
}
__device__ __forceinline__ float sigm(float x) {
    return fastrcp(1.0f + __expf(-x));
}
// tanh(x) = 1 - 2/(exp(2x)+1); saturates correctly via exp overflow/underflow.
__device__ __forceinline__ float tanh_fast(float x) {
    return 1.0f - 2.0f * fastrcp(1.0f + __expf(2.0f * x));
}
__device__ __forceinline__ float dot2(unsigned int a, unsigned int b, float acc) {
#if __has_builtin(__builtin_amdgcn_fdot2)
    return __builtin_amdgcn_fdot2(__builtin_bit_cast(h2_t, a),
                                  __builtin_bit_cast(h2_t, b), acc, false);
#else
    h2_t av = __builtin_bit_cast(h2_t, a);
    h2_t bv = __builtin_bit_cast(h2_t, b);
    return acc + (float)av.x * (float)bv.x + (float)av.y * (float)bv.y;
#endif
}
__device__ __forceinline__ unsigned int packh2(float a, float b) {
    h2_t v; v.x = (_Float16)a; v.y = (_Float16)b;
    return __builtin_bit_cast(unsigned int, v);
}

// One WG per batch element (256 WGs, 1/CU), 512 threads = 8 waves.
// X = obs@Wi + b computed per 16-step chunk via MFMA 16x16x32_f16 (M = t-rows)
// into LDS -> x-projection off the serial chain. Scan step: thread (g=tid>>2,
// q=tid&3) computes K-quarter partials of gates {g, g+128, g+256, g+384} via
// v_dot2 (wh in 64 VGPRs), reduces in-wave via 2-stage shfl_xor (DPP quads),
// activations redundantly per quad (bitwise-identical), carry in regs.
// 1 barrier/step (parity-double-buffered h in LDS).
__global__ __launch_bounds__(512, 2) void lstm_scan_kernel(
    const float* __restrict__ obs, const int* __restrict__ done,
    const float* __restrict__ c0, const float* __restrict__ h0,
    const float* __restrict__ Wi, const float* __restrict__ Wh,
    const float* __restrict__ bvec, float* __restrict__ out)
{
    const int b    = blockIdx.x;
    const int tid  = threadIdx.x;
    const int lane = tid & 63;
    const int wave = tid >> 6;
    const int g    = tid >> 2;   // h-index 0..127
    const int q    = tid & 3;    // K-quarter 0..3

    __shared__ float X_lds[CH][G_DIM];              // 32 KB, gates-pre-act per chunk
    __shared__ __align__(16) __half h_buf[2][H_DIM];
    __shared__ int dchunk[CH];

    // ---- Wh columns for this thread's 4 gates, K-quarter q (64 VGPRs packed f16)
    unsigned int wh[4][16];
#pragma unroll
    for (int u = 0; u < 4; ++u) {
        const int col = g + 128 * u;
#pragma unroll
        for (int kk = 0; kk < 16; ++kk) {
            const int k = q * 32 + 2 * kk;
            wh[u][kk] = packh2(Wh[k * G_DIM + col], Wh[(k + 1) * G_DIM + col]);
        }
    }

    // ---- Wi as MFMA B-fragments: wave owns n-tiles {4w..4w+3}; per (tile,kstep)
    // lane holds Wi[k][n], n = nt*16+(lane&15), k = ks*32 + 8*(lane>>4) + j.
    // Same k-formula used for A -> k-permutation-invariant product.
    f16x8 wif[4][4];
#pragma unroll
    for (int i = 0; i < 4; ++i) {
        const int n = (wave * 4 + i) * 16 + (lane & 15);
#pragma unroll
        for (int ks = 0; ks < 4; ++ks) {
            f16x8 f;
#pragma unroll
            for (int j = 0; j < 8; ++j) {
                const int k = ks * 32 + 8 * (lane >> 4) + j;
                f[j] = (_Float16)Wi[k * G_DIM + n];
            }
            wif[i][ks] = f;
        }
    }
    float bias_nt[4];
#pragma unroll
    for (int i = 0; i < 4; ++i)
        bias_nt[i] = bvec[(wave * 4 + i) * 16 + (lane & 15)];

    float c     = c0[b * H_DIM + g];
    float hlast = h0[b * H_DIM + g];
    if (tid < H_DIM) h_buf[0][tid] = __float2half(h0[b * H_DIM + tid]);

    // ---- obs A-staging for chunk 0: lane covers row t0+(lane&15), 8 floats/kstep
    const int arow  = lane & 15;
    const int kbase = 8 * (lane >> 4);
    float4 st0, st1, st2, st3, st4, st5, st6, st7;
    {
        const float* p = obs + ((size_t)(0 + arow) * B_DIM + b) * D_DIM + kbase;
        st0 = *(const float4*)(p + 0 * 32); st1 = *(const float4*)(p + 0 * 32 + 4);
        st2 = *(const float4*)(p + 1 * 32); st3 = *(const float4*)(p + 1 * 32 + 4);
        st4 = *(const float4*)(p + 2 * 32); st5 = *(const float4*)(p + 2 * 32 + 4);
        st6 = *(const float4*)(p + 3 * 32); st7 = *(const float4*)(p + 3 * 32 + 4);
    }
    int dreg = 0;
    if (tid < CH) dreg = done[(0 + tid) * B_DIM + b];

#define CVT8(DST, A, B)                                                        \
    { f16x8 f_;                                                                \
      f_[0] = (_Float16)(A).x; f_[1] = (_Float16)(A).y;                        \
      f_[2] = (_Float16)(A).z; f_[3] = (_Float16)(A).w;                        \
      f_[4] = (_Float16)(B).x; f_[5] = (_Float16)(B).y;                        \
      f_[6] = (_Float16)(B).z; f_[7] = (_Float16)(B).w; DST = f_; }

    for (int ci = 0; ci < T_DIM / CH; ++ci) {
        const int t0 = ci * CH;

        // done flags for this chunk (prev step-15 barrier ordered prior reads)
        if (tid < CH) dchunk[tid] = dreg;

        // staging -> A-fragments (f16)
        f16x8 a0, a1, a2, a3;
        CVT8(a0, st0, st1) CVT8(a1, st2, st3) CVT8(a2, st4, st5) CVT8(a3, st6, st7)

        // X[t0..t0+15][:] = obs-chunk @ Wi + bias   (8 MFMA per wave)
#pragma unroll
        for (int i = 0; i < 4; ++i) {
            f32x4 acc;
            acc[0] = acc[1] = acc[2] = acc[3] = bias_nt[i];
            acc = __builtin_amdgcn_mfma_f32_16x16x32_f16(a0, wif[i][0], acc, 0, 0, 0);
            acc = __builtin_amdgcn_mfma_f32_16x16x32_f16(a1, wif[i][1], acc, 0, 0, 0);
            acc = __builtin_amdgcn_mfma_f32_16x16x32_f16(a2, wif[i][2], acc, 0, 0, 0);
            acc = __builtin_amdgcn_mfma_f32_16x16x32_f16(a3, wif[i][3], acc, 0, 0, 0);
            const int n = (wave * 4 + i) * 16 + (lane & 15);
#pragma unroll
            for (int r = 0; r < 4; ++r)
                X_lds[(lane >> 4) * 4 + r][n] = acc[r];   // C/D: row=(l>>4)*4+r, col=l&15 (m89)
        }
        __syncthreads();   // X_lds + dchunk + h_buf visible

        // prefetch obs + done for next chunk (lands during the 16 steps)
        const int tn = (t0 + CH <= T_DIM - CH) ? (t0 + CH) : (T_DIM - CH);
        {
            const float* p = obs + ((size_t)(tn + arow) * B_DIM + b) * D_DIM + kbase;
            st0 = *(const float4*)(p + 0 * 32); st1 = *(const float4*)(p + 0 * 32 + 4);
            st2 = *(const float4*)(p + 1 * 32); st3 = *(const float4*)(p + 1 * 32 + 4);
            st4 = *(const float4*)(p + 2 * 32); st5 = *(const float4*)(p + 2 * 32 + 4);
            st6 = *(const float4*)(p + 3 * 32); st7 = *(const float4*)(p + 3 * 32 + 4);
        }
        if (tid < CH) dreg = done[(tn + tid) * B_DIM + b];

        // ---- 16 serial LSTM steps
#pragma unroll 4
        for (int s = 0; s < CH; ++s) {
            const int t  = t0 + s;
            const int p  = t & 1;
            const int dm = dchunk[s];

            const float xg0 = X_lds[s][g];
            const float xg1 = X_lds[s][g + 128];
            const float xg2 = X_lds[s][g + 256];
            const float xg3 = X_lds[s][g + 384];

            // h K-quarter: 32 f16 = 4 x b128 (4 distinct addrs/wave -> broadcast)
            const uint4* hp = (const uint4*)&h_buf[p][q * 32];
            unsigned int hu[16];
            *(uint4*)&hu[0]  = hp[0];
            *(uint4*)&hu[4]  = hp[1];
            *(uint4*)&hu[8]  = hp[2];
            *(uint4*)&hu[12] = hp[3];

            float s0 = 0.f, s1 = 0.f, s2 = 0.f, s3 = 0.f;
#pragma unroll
            for (int kk = 0; kk < 16; ++kk) {
                s0 = dot2(hu[kk], wh[0][kk], s0);
                s1 = dot2(hu[kk], wh[1][kk], s1);
                s2 = dot2(hu[kk], wh[2][kk], s2);
                s3 = dot2(hu[kk], wh[3][kk], s3);
            }
            // quad reduce (lanes q=0..3 hold K-quarters; DPP, bitwise-identical)
            s0 += __shfl_xor(s0, 1); s0 += __shfl_xor(s0, 2);
            s1 += __shfl_xor(s1, 1); s1 += __shfl_xor(s1, 2);
            s2 += __shfl_xor(s2, 1); s2 += __shfl_xor(s2, 2);
            s3 += __shfl_xor(s3, 1); s3 += __shfl_xor(s3, 2);

            const float gi = xg0 + (dm ? 0.f : s0);
            const float gf = xg1 + (dm ? 0.f : s1);
            const float gg = xg2 + (dm ? 0.f : s2);
            const float go = xg3 + (dm ? 0.f : s3);

            const float ai = sigm(gi);
            const float af = sigm(gf);
            const float ag = tanh_fast(gg);
            const float ao = sigm(go);

            const float cp = dm ? 0.f : c;
            c = af * cp + ai * ag;
            const float hn = ao * tanh_fast(c);
            hlast = hn;

            if (q == 0) {
                out[((size_t)t * B_DIM + b) * H_DIM + g] = hn;
                h_buf[p ^ 1][g] = __float2half(hn);
            }
            __syncthreads();   // h_buf[p^1] ready; also orders next overwrite of [p]
        }
    }

    // final carries: c_f then h_f after y
    if (q == 0) {
        const size_t ybase = (size_t)T_DIM * B_DIM * H_DIM;
        out[ybase + (size_t)b * H_DIM + g] = c;
        out[ybase + (size_t)B_DIM * H_DIM + (size_t)b * H_DIM + g] = hlast;
    }
#undef CVT8
}

extern "C" void kernel_launch(void* const* d_in, const int* in_sizes, int n_in,
                              void* d_out, int out_size, void* d_ws, size_t ws_size,
                              hipStream_t stream) {
    const float* obs  = (const float*)d_in[0];
    const int*   done = (const int*)d_in[1];
    const float* c0   = (const float*)d_in[2];
    const float* h0   = (const float*)d_in[3];
    const float* Wi   = (const float*)d_in[4];
    const float* Wh   = (const float*)d_in[5];
    const float* bv   = (const float*)d_in[6];
    float* out = (float*)d_out;

    lstm_scan_kernel<<<dim3(B_DIM), dim3(512), 0, stream>>>(
        obs, done, c0, h0, Wi, Wh, bv, out);
}